// Round 9
// baseline (184.123 us; speedup 1.0000x reference)
//
#include <hip/hip_runtime.h>

#define NF 512
#define NH 3
#define NC 7
#define RB 128         // rows per dst bucket (power of two)
#define RBS 7          // log2(RB)
#define NBMAX 1024     // max buckets (N <= 131072)
#define SORTB 128      // sort role blocks in K1
#define OVFCAP 65536   // overflow record capacity

// ---------- common ----------

__device__ __forceinline__ int load_idx(const void* base, long long i, int is32) {
    return is32 ? ((const int*)base)[i] : (int)((const long long*)base)[i];
}

__device__ __forceinline__ int detect_is32(const int* __restrict__ ei, int E, int* anynz) {
    if (threadIdx.x == 0) *anynz = 0;
    __syncthreads();
    int lim = E < 2048 ? E : 2048;
    int nz = 0;
    for (int i = threadIdx.x; i < lim; i += blockDim.x) nz |= ei[2 * i + 1];
    if (nz) atomicOr(anynz, 1);
    __syncthreads();
    return *anynz;
}

// GEMM role: grid-stride waves over rows [row0,row1), W slice in registers.
// Writes y4[row].xyz = x[row]@W (UNSCALED). Never touches .w (deg owns it).
__device__ __forceinline__ void gemm_rows(const float* __restrict__ x, const float* __restrict__ W,
                                          float* __restrict__ y4f, int row0, int row1,
                                          int wid, int nwaves) {
    int lane = threadIdx.x & 63;
    float4 w4[6];
    const float4* wp = (const float4*)W;
#pragma unroll
    for (int j = 0; j < 6; ++j) w4[j] = wp[lane * 6 + j];
    const float* wf = (const float*)w4;
    for (int row = row0 + wid; row < row1; row += nwaves) {
        const float4* xp = (const float4*)(x + (size_t)row * NF) + lane * 2;
        float4 a = xp[0], b = xp[1];
        float xv[8] = {a.x, a.y, a.z, a.w, b.x, b.y, b.z, b.w};
        float s0 = 0.f, s1 = 0.f, s2 = 0.f;
#pragma unroll
        for (int j = 0; j < 8; ++j) {
            s0 += xv[j] * wf[j * 3 + 0];
            s1 += xv[j] * wf[j * 3 + 1];
            s2 += xv[j] * wf[j * 3 + 2];
        }
#pragma unroll
        for (int off = 32; off; off >>= 1) {
            s0 += __shfl_down(s0, off);
            s1 += __shfl_down(s1, off);
            s2 += __shfl_down(s2, off);
        }
        if (lane == 0) {
            *(float2*)(y4f + 4 * (size_t)row) = make_float2(s0, s1);
            y4f[4 * (size_t)row + 2] = s2;
        }
    }
}

// ---------- fast path (3 kernels + memset) ----------

// K1: blocks [0,SORTB): one-pass bucket scatter via block-hist + global reservation.
//     blocks [SORTB,..): gemm rows [0,row1). gcur[b] = used slots in bucket b (memset 0);
//     gcur[NBv] = overflow count.
__global__ __launch_bounds__(256) void k_sortgemm(const void* __restrict__ ei,
                                                  int* __restrict__ gcur,
                                                  unsigned* __restrict__ recs,
                                                  int2* __restrict__ ovf,
                                                  int E, int NBv, int CAP,
                                                  const float* __restrict__ x, const float* __restrict__ W,
                                                  float* __restrict__ y4f, int row1) {
    __shared__ int cnt[NBMAX];   // pass1: counts; after reserve: global cursors
    __shared__ int anynz;
    if (blockIdx.x < SORTB) {
        int is32 = detect_is32((const int*)ei, E, &anynz);
        int t = threadIdx.x;
        for (int i = t; i < NBv; i += 256) cnt[i] = 0;
        __syncthreads();
        int EB = (E + SORTB - 1) / SORTB;
        int e0 = blockIdx.x * EB;
        int e1 = min(E, e0 + EB);
        for (int i = e0 + t; i < e1; i += 256) {
            int d = load_idx(ei, (long long)E + i, is32);
            atomicAdd(&cnt[d >> RBS], 1);
        }
        __syncthreads();
        for (int b = t; b < NBv; b += 256) {
            int c = cnt[b];
            int base = c ? atomicAdd(&gcur[b], c) : 0;
            cnt[b] = b * CAP + base;          // global write cursor for this block
        }
        __syncthreads();
        for (int i = e0 + t; i < e1; i += 256) {
            int sv = load_idx(ei, i, is32);
            int d = load_idx(ei, (long long)E + i, is32);
            int b = d >> RBS;
            int pos = atomicAdd(&cnt[b], 1);
            if (pos < b * CAP + CAP) {
                recs[pos] = ((unsigned)(d & (RB - 1)) << 17) | (unsigned)sv;
            } else {
                int op = atomicAdd(&gcur[NBv], 1);
                if (op < OVFCAP) ovf[op] = make_int2(sv, d);
            }
        }
    } else {
        int gb = gridDim.x - SORTB;
        gemm_rows(x, W, y4f, 0, row1, (blockIdx.x - SORTB) * 4 + (threadIdx.x >> 6), gb * 4);
    }
}

// K2: blocks [0,NBv): per-bucket in-degree -> y4[row].w = rsqrt(deg+1);
//     blocks [NBv,..): gemm rows [row1,N).
__global__ __launch_bounds__(256) void k_deggemm(const unsigned* __restrict__ recs,
                                                 const int* __restrict__ gcur,
                                                 const int2* __restrict__ ovf,
                                                 float* __restrict__ y4f, int n, int NBv, int CAP,
                                                 const float* __restrict__ x, const float* __restrict__ W,
                                                 int row1) {
    __shared__ int c128[RB];
    if (blockIdx.x < (unsigned)NBv) {
        int t = threadIdx.x;
        for (int i = t; i < RB; i += 256) c128[i] = 0;
        __syncthreads();
        int b = blockIdx.x;
        int cntb = min(gcur[b], CAP);
        int i0 = b * CAP, i1 = i0 + cntb;
        for (int i = i0 + t; i < i1; i += 256)
            atomicAdd(&c128[recs[i] >> 17], 1);
        int oc = min(gcur[NBv], OVFCAP);
        for (int j = t; j < oc; j += 256) {
            int2 e = ovf[j];
            if ((e.y >> RBS) == b) atomicAdd(&c128[e.y & (RB - 1)], 1);
        }
        __syncthreads();
        int rbase = b << RBS;
        for (int r = t; r < RB; r += 256) {
            int row = rbase + r;
            if (row < n) y4f[4 * (size_t)row + 3] = rsqrtf((float)(c128[r] + 1));
        }
    } else {
        int gb = gridDim.x - NBv;
        gemm_rows(x, W, y4f, row1, n, (blockIdx.x - NBv) * 4 + (threadIdx.x >> 6), gb * 4);
    }
}

// K3: one block per bucket: u[d] = sum dis[s]*xw[s] (dis rides in y4.w -> ONE 16B
// gather per record, 4x unrolled), then finalize + out GEMM.
__global__ __launch_bounds__(256) void k_aggfinal(const unsigned* __restrict__ recs,
                                                  const int* __restrict__ gcur,
                                                  const int2* __restrict__ ovf,
                                                  const float4* __restrict__ y4, const float* __restrict__ bg,
                                                  const float* __restrict__ Wo, const float* __restrict__ bo,
                                                  float* __restrict__ outH, float* __restrict__ outZ,
                                                  int n, int NBv, int CAP) {
    __shared__ float u[RB * 3];
    int t = threadIdx.x;
    for (int i = t; i < RB * 3; i += 256) u[i] = 0.f;
    __syncthreads();
    int b = blockIdx.x;
    int cntb = min(gcur[b], CAP);
    int i0 = b * CAP, i1 = i0 + cntb;
    int i = i0 + t;
    for (; i + 768 < i1; i += 1024) {
        unsigned r0 = recs[i], r1 = recs[i + 256], r2 = recs[i + 512], r3 = recs[i + 768];
        float4 v0 = y4[r0 & 0x1FFFF], v1 = y4[r1 & 0x1FFFF],
               v2 = y4[r2 & 0x1FFFF], v3 = y4[r3 & 0x1FFFF];
        atomicAdd(&u[(r0 >> 17) * 3 + 0], v0.w * v0.x);
        atomicAdd(&u[(r0 >> 17) * 3 + 1], v0.w * v0.y);
        atomicAdd(&u[(r0 >> 17) * 3 + 2], v0.w * v0.z);
        atomicAdd(&u[(r1 >> 17) * 3 + 0], v1.w * v1.x);
        atomicAdd(&u[(r1 >> 17) * 3 + 1], v1.w * v1.y);
        atomicAdd(&u[(r1 >> 17) * 3 + 2], v1.w * v1.z);
        atomicAdd(&u[(r2 >> 17) * 3 + 0], v2.w * v2.x);
        atomicAdd(&u[(r2 >> 17) * 3 + 1], v2.w * v2.y);
        atomicAdd(&u[(r2 >> 17) * 3 + 2], v2.w * v2.z);
        atomicAdd(&u[(r3 >> 17) * 3 + 0], v3.w * v3.x);
        atomicAdd(&u[(r3 >> 17) * 3 + 1], v3.w * v3.y);
        atomicAdd(&u[(r3 >> 17) * 3 + 2], v3.w * v3.z);
    }
    for (; i < i1; i += 256) {
        unsigned rec = recs[i];
        float4 v = y4[rec & 0x1FFFF];
        int r = rec >> 17;
        atomicAdd(&u[r * 3 + 0], v.w * v.x);
        atomicAdd(&u[r * 3 + 1], v.w * v.y);
        atomicAdd(&u[r * 3 + 2], v.w * v.z);
    }
    int oc = min(gcur[NBv], OVFCAP);
    for (int j = t; j < oc; j += 256) {
        int2 e = ovf[j];
        if ((e.y >> RBS) == b) {
            float4 v = y4[e.x];
            int r = e.y & (RB - 1);
            atomicAdd(&u[r * 3 + 0], v.w * v.x);
            atomicAdd(&u[r * 3 + 1], v.w * v.y);
            atomicAdd(&u[r * 3 + 2], v.w * v.z);
        }
    }
    __syncthreads();
    float b0 = bg[0], b1 = bg[1], b2 = bg[2];
    int rbase = b << RBS;
    for (int r = t; r < RB; r += 256) {
        int row = rbase + r;
        if (row >= n) break;
        float4 yv = y4[row];
        float di = yv.w;
        float h0 = fmaxf(di * (u[r * 3 + 0] + di * yv.x) + b0, 0.f);
        float h1 = fmaxf(di * (u[r * 3 + 1] + di * yv.y) + b1, 0.f);
        float h2 = fmaxf(di * (u[r * 3 + 2] + di * yv.z) + b2, 0.f);
        outH[row * 3 + 0] = h0; outH[row * 3 + 1] = h1; outH[row * 3 + 2] = h2;
#pragma unroll
        for (int c = 0; c < NC; ++c)
            outZ[row * NC + c] = h0 * Wo[c] + h1 * Wo[NC + c] + h2 * Wo[2 * NC + c] + bo[c];
    }
}

// ---------- atomic fallback (round-1 structure) ----------

__global__ void k_detect_fb(const int* ei, int* flag, int E) {
    __shared__ int anynz;
    if (threadIdx.x == 0) anynz = 0;
    __syncthreads();
    int lim = E < 2048 ? E : 2048;
    int nz = 0;
    for (int i = threadIdx.x; i < lim; i += blockDim.x) nz |= ei[2 * i + 1];
    if (nz) atomicOr(&anynz, 1);
    __syncthreads();
    if (threadIdx.x == 0) *flag = anynz;
}
__global__ void k_init_fb(float* deg, int n) {
    int i = blockIdx.x * blockDim.x + threadIdx.x;
    if (i < n) deg[i] = 1.0f;
}
__global__ void k_degc_fb(const void* ei, const int* flag, float* deg, int E, int n) {
    int i = blockIdx.x * blockDim.x + threadIdx.x;
    if (i >= E) return;
    int d = load_idx(ei, (long long)E + i, *flag);
    if ((unsigned)d < (unsigned)n) atomicAdd(&deg[d], 1.0f);
}
__global__ __launch_bounds__(256) void k_gemm_fb(const float* x, const float* W, float* degdis,
                                                 float* xw, float* agg, int n) {
    __shared__ float wl[NF * NH];
    for (int j = threadIdx.x; j < NF * NH; j += 256) wl[j] = W[j];
    __syncthreads();
    int row = blockIdx.x * 4 + (threadIdx.x >> 6);
    if (row >= n) return;
    int lane = threadIdx.x & 63;
    const float4* xp = (const float4*)(x + (size_t)row * NF + lane * 8);
    float4 a = xp[0], b = xp[1];
    float xv[8] = {a.x, a.y, a.z, a.w, b.x, b.y, b.z, b.w};
    float s0 = 0.f, s1 = 0.f, s2 = 0.f;
    int f0 = lane * 8;
#pragma unroll
    for (int j = 0; j < 8; ++j) {
        float v = xv[j];
        const float* wp = &wl[(f0 + j) * NH];
        s0 += v * wp[0]; s1 += v * wp[1]; s2 += v * wp[2];
    }
#pragma unroll
    for (int off = 32; off; off >>= 1) {
        s0 += __shfl_down(s0, off); s1 += __shfl_down(s1, off); s2 += __shfl_down(s2, off);
    }
    if (lane == 0) {
        float d = degdis[row];
        float di = d > 0.f ? rsqrtf(d) : 0.f;
        degdis[row] = di;
        xw[row * 3 + 0] = s0; xw[row * 3 + 1] = s1; xw[row * 3 + 2] = s2;
        float n2 = di * di;
        agg[row * 3 + 0] = s0 * n2; agg[row * 3 + 1] = s1 * n2; agg[row * 3 + 2] = s2 * n2;
    }
}
__global__ void k_scat_fb(const void* ei, const int* flag, const float* dis, const float* xw,
                          float* agg, int E, int n) {
    int i = blockIdx.x * blockDim.x + threadIdx.x;
    if (i >= E) return;
    int is32 = *flag;
    int s = load_idx(ei, i, is32);
    int d = load_idx(ei, (long long)E + i, is32);
    if ((unsigned)s >= (unsigned)n || (unsigned)d >= (unsigned)n) return;
    float w = dis[s] * dis[d];
    atomicAdd(&agg[d * 3 + 0], xw[s * 3 + 0] * w);
    atomicAdd(&agg[d * 3 + 1], xw[s * 3 + 1] * w);
    atomicAdd(&agg[d * 3 + 2], xw[s * 3 + 2] * w);
}
__global__ void k_final_fb(const float* agg, const float* bg, const float* Wo, const float* bo,
                           float* outH, float* outZ, int n) {
    int i = blockIdx.x * blockDim.x + threadIdx.x;
    if (i >= n) return;
    float h0 = fmaxf(agg[i * 3 + 0] + bg[0], 0.f);
    float h1 = fmaxf(agg[i * 3 + 1] + bg[1], 0.f);
    float h2 = fmaxf(agg[i * 3 + 2] + bg[2], 0.f);
    outH[i * 3 + 0] = h0; outH[i * 3 + 1] = h1; outH[i * 3 + 2] = h2;
#pragma unroll
    for (int c = 0; c < NC; ++c)
        outZ[i * NC + c] = h0 * Wo[c] + h1 * Wo[NC + c] + h2 * Wo[2 * NC + c] + bo[c];
}

// ---------- launch ----------

extern "C" void kernel_launch(void* const* d_in, const int* in_sizes, int n_in,
                              void* d_out, int out_size, void* d_ws, size_t ws_size,
                              hipStream_t stream) {
    const float* x  = (const float*)d_in[0];
    const void*  ei = d_in[1];
    const float* Wg = (const float*)d_in[2];
    const float* bg = (const float*)d_in[3];
    const float* Wo = (const float*)d_in[4];
    const float* bo = (const float*)d_in[5];

    const int N = in_sizes[0] / NF;
    const int E = in_sizes[1] / 2;
    const int NBv = (N + RB - 1) >> RBS;
    // per-bucket capacity: ~2x mean, rounded up to 1KB multiple, >= 1024
    int CAP = (int)((2LL * E / (NBv > 0 ? NBv : 1) + 1023) & ~1023LL);
    if (CAP < 1024) CAP = 1024;

    float* outH = (float*)d_out;
    float* outZ = outH + (size_t)3 * N;

    int*   wsI = (int*)d_ws;
    float* wsF = (float*)d_ws;

    size_t off = 64;
    int* gcur  = wsI + off; off += NBMAX + 16;
    int2* ovf  = (int2*)(wsI + off); off += (size_t)2 * OVFCAP;
    off = (off + 3) & ~(size_t)3;
    float* y4  = wsF + off; off += (size_t)4 * N;
    unsigned* recs = (unsigned*)(wsI + off); off += (size_t)NBv * CAP;

    bool fast = (off * 4 <= ws_size) && (N <= 131072) && (NBv <= NBMAX) && (E > 0);

    if (fast) {
        int r1 = (int)((long long)N * 70 / 100);
        hipMemsetAsync(gcur, 0, (NBv + 1) * sizeof(int), stream);
        k_sortgemm<<<SORTB + 1792, dim3(256), 0, stream>>>(ei, gcur, recs, ovf, E, NBv, CAP,
                                                           x, Wg, y4, r1);
        k_deggemm<<<NBv + 768, dim3(256), 0, stream>>>(recs, gcur, ovf, y4, N, NBv, CAP,
                                                       x, Wg, r1);
        k_aggfinal<<<NBv, dim3(256), 0, stream>>>(recs, gcur, ovf, (const float4*)y4,
                                                  bg, Wo, bo, outH, outZ, N, NBv, CAP);
    } else {
        int* flag  = wsI;
        float* deg = wsF + 64;
        float* xw  = deg + N;
        float* agg = xw + (size_t)3 * N;
        int gN = (N + 255) / 256, gE = (E + 255) / 256;
        dim3 blk(256);
        k_detect_fb<<<1, blk, 0, stream>>>((const int*)ei, flag, E);
        k_init_fb<<<gN, blk, 0, stream>>>(deg, N);
        k_degc_fb<<<gE, blk, 0, stream>>>(ei, flag, deg, E, N);
        k_gemm_fb<<<(N + 3) / 4, blk, 0, stream>>>(x, Wg, deg, xw, agg, N);
        k_scat_fb<<<gE, blk, 0, stream>>>(ei, flag, deg, xw, agg, E, N);
        k_final_fb<<<gN, blk, 0, stream>>>(agg, bg, Wo, bo, outH, outZ, N);
    }
}

// Round 10
// 160.136 us; speedup vs baseline: 1.1498x; 1.1498x over previous
//
#include <hip/hip_runtime.h>

#define NF 512
#define NH 3
#define NC 7
#define RB 128         // rows per dst bucket (power of two)
#define RBS 7          // log2(RB)
#define G1 256         // edge slice blocks for hist/sort
#define NBMAX 1024     // max buckets (N <= 131072)

// ---------- common ----------

__device__ __forceinline__ int load_idx(const void* base, long long i, int is32) {
    return is32 ? ((const int*)base)[i] : (int)((const long long*)base)[i];
}

// Per-block inline dtype detection: int64 layout has all-odd-words zero over the
// first 2048 pairs; int32 layout has (almost surely) nonzero there.
__device__ __forceinline__ int detect_is32(const int* __restrict__ ei, int E, int* anynz) {
    if (threadIdx.x == 0) *anynz = 0;
    __syncthreads();
    int lim = E < 2048 ? E : 2048;
    int nz = 0;
    for (int i = threadIdx.x; i < lim; i += blockDim.x) nz |= ei[2 * i + 1];
    if (nz) atomicOr(anynz, 1);
    __syncthreads();
    return *anynz;
}

// GEMM role: grid-stride waves over rows [row0,row1), W slice in registers.
// Writes y4[row].xyz = x[row]@W (UNSCALED). Never touches .w (deg owns it).
__device__ __forceinline__ void gemm_rows(const float* __restrict__ x, const float* __restrict__ W,
                                          float* __restrict__ y4f, int row0, int row1,
                                          int wid, int nwaves) {
    int lane = threadIdx.x & 63;
    float4 w4[6];
    const float4* wp = (const float4*)W;
#pragma unroll
    for (int j = 0; j < 6; ++j) w4[j] = wp[lane * 6 + j];
    const float* wf = (const float*)w4;
    for (int row = row0 + wid; row < row1; row += nwaves) {
        const float4* xp = (const float4*)(x + (size_t)row * NF) + lane * 2;
        float4 a = xp[0], b = xp[1];
        float xv[8] = {a.x, a.y, a.z, a.w, b.x, b.y, b.z, b.w};
        float s0 = 0.f, s1 = 0.f, s2 = 0.f;
#pragma unroll
        for (int j = 0; j < 8; ++j) {
            s0 += xv[j] * wf[j * 3 + 0];
            s1 += xv[j] * wf[j * 3 + 1];
            s2 += xv[j] * wf[j * 3 + 2];
        }
#pragma unroll
        for (int off = 32; off; off >>= 1) {
            s0 += __shfl_down(s0, off);
            s1 += __shfl_down(s1, off);
            s2 += __shfl_down(s2, off);
        }
        if (lane == 0) {
            *(float2*)(y4f + 4 * (size_t)row) = make_float2(s0, s1);
            y4f[4 * (size_t)row + 2] = s2;
        }
    }
}

// ---------- fast path (5 kernels, gemm co-scheduled with CSR phases) ----------

// K1 (512thr): blocks [0,G1) histogram their edge slice; rest gemm rows [0,row1)
__global__ __launch_bounds__(512) void k_histgemm(const void* __restrict__ ei, int* __restrict__ hist,
                                                  int E, int NBv,
                                                  const float* __restrict__ x, const float* __restrict__ W,
                                                  float* __restrict__ y4f, int row1) {
    __shared__ int cnt[NBMAX];
    __shared__ int anynz;
    if (blockIdx.x < G1) {
        int is32 = detect_is32((const int*)ei, E, &anynz);
        for (int i = threadIdx.x; i < NBv; i += 512) cnt[i] = 0;
        __syncthreads();
        int EB = (E + G1 - 1) / G1;
        int e0 = blockIdx.x * EB;
        int e1 = min(E, e0 + EB);
        for (int i = e0 + threadIdx.x; i < e1; i += 512) {
            int d = load_idx(ei, (long long)E + i, is32);
            atomicAdd(&cnt[d >> RBS], 1);
        }
        __syncthreads();
        for (int b = threadIdx.x; b < NBv; b += 512)
            hist[b * G1 + blockIdx.x] = cnt[b];
    } else {
        int gb = gridDim.x - G1;
        gemm_rows(x, W, y4f, 0, row1, (blockIdx.x - G1) * 8 + (threadIdx.x >> 6), gb * 8);
    }
}

// K2 (256thr): blocks [0,NBv) per-bucket exclusive scan of G1 counts; rest gemm [row1,row2)
__global__ __launch_bounds__(256) void k_scangemm(int* __restrict__ hist, int* __restrict__ bcount,
                                                  int NBv,
                                                  const float* __restrict__ x, const float* __restrict__ W,
                                                  float* __restrict__ y4f, int row1, int row2) {
    __shared__ int wsum[4];
    if (blockIdx.x < (unsigned)NBv) {
        int b = blockIdx.x;
        int t = threadIdx.x, lane = t & 63, w = t >> 6;
        int v = hist[b * G1 + t];
        int incl = v;
#pragma unroll
        for (int off = 1; off < 64; off <<= 1) {
            int tt = __shfl_up(incl, off);
            if (lane >= off) incl += tt;
        }
        if (lane == 63) wsum[w] = incl;
        __syncthreads();
        int p = 0;
        for (int j = 0; j < w; ++j) p += wsum[j];
        hist[b * G1 + t] = p + incl - v;          // bucket-local exclusive
        if (t == 255) bcount[b] = p + incl;       // bucket total
    } else {
        int gb = gridDim.x - NBv;
        gemm_rows(x, W, y4f, row1, row2, (blockIdx.x - NBv) * 4 + (threadIdx.x >> 6), gb * 4);
    }
}

// K3 (512thr): blocks [0,G1) counting-sort scatter (redundant bstart scan from bcount);
//     rest gemm rows [row2,row3). Block 0 persists bstart.
__global__ __launch_bounds__(512) void k_sortgemm(const void* __restrict__ ei,
                                                  const int* __restrict__ hist,
                                                  const int* __restrict__ bcount,
                                                  int* __restrict__ bstart,
                                                  unsigned* __restrict__ recs, int E, int NBv,
                                                  const float* __restrict__ x, const float* __restrict__ W,
                                                  float* __restrict__ y4f, int row2, int row3) {
    __shared__ int bst[NBMAX];
    __shared__ int cur[NBMAX];
    __shared__ int wsum[8];
    __shared__ int anynz;
    if (blockIdx.x < G1) {
        int is32 = detect_is32((const int*)ei, E, &anynz);
        int t = threadIdx.x, lane = t & 63, w = t >> 6;
        // exclusive prefix over NBv bucket totals: 2 values/thread, 1024 slots
        int i0p = 2 * t, i1p = 2 * t + 1;
        int v0 = (i0p < NBv) ? bcount[i0p] : 0;
        int v1 = (i1p < NBv) ? bcount[i1p] : 0;
        int s = v0 + v1;
        int incl = s;
#pragma unroll
        for (int off = 1; off < 64; off <<= 1) {
            int tt = __shfl_up(incl, off);
            if (lane >= off) incl += tt;
        }
        if (lane == 63) wsum[w] = incl;
        __syncthreads();
        int p = 0;
        for (int j = 0; j < w; ++j) p += wsum[j];
        int excl = p + incl - s;
        bst[i0p] = excl;
        bst[i1p] = excl + v0;
        __syncthreads();
        for (int b = t; b < NBv; b += 512)
            cur[b] = bst[b] + hist[b * G1 + blockIdx.x];
        if (blockIdx.x == 0)
            for (int b = t; b < NBv; b += 512) bstart[b] = bst[b];
        __syncthreads();
        int EB = (E + G1 - 1) / G1;
        int e0 = blockIdx.x * EB;
        int e1 = min(E, e0 + EB);
        for (int i = e0 + t; i < e1; i += 512) {
            int sv = load_idx(ei, i, is32);
            int d = load_idx(ei, (long long)E + i, is32);
            int b = d >> RBS;
            int pos = atomicAdd(&cur[b], 1);      // LDS cursor only
            recs[pos] = ((unsigned)(d & (RB - 1)) << 17) | (unsigned)sv;
        }
    } else {
        int gb = gridDim.x - G1;
        gemm_rows(x, W, y4f, row2, row3, (blockIdx.x - G1) * 8 + (threadIdx.x >> 6), gb * 8);
    }
}

// K4 (512thr): blocks [0,NBv) per-bucket in-degree -> y4[row].w = rsqrt(deg+1);
//     rest gemm rows [row3,N). Disjoint bytes of y4, no race.
__global__ __launch_bounds__(512) void k_deggemm(const unsigned* __restrict__ recs,
                                                 const int* __restrict__ bstart, const int* __restrict__ bcount,
                                                 float* __restrict__ y4f, int n, int NBv,
                                                 const float* __restrict__ x, const float* __restrict__ W,
                                                 int row3) {
    __shared__ int cnt[RB];
    if (blockIdx.x < (unsigned)NBv) {
        for (int i = threadIdx.x; i < RB; i += 512) cnt[i] = 0;
        __syncthreads();
        int b = blockIdx.x;
        int s0 = bstart[b], s1 = s0 + bcount[b];
        for (int i = s0 + threadIdx.x; i < s1; i += 512)
            atomicAdd(&cnt[recs[i] >> 17], 1);
        __syncthreads();
        int rbase = b << RBS;
        for (int r = threadIdx.x; r < RB; r += 512) {
            int row = rbase + r;
            if (row < n) y4f[4 * (size_t)row + 3] = rsqrtf((float)(cnt[r] + 1));
        }
    } else {
        int gb = gridDim.x - NBv;
        gemm_rows(x, W, y4f, row3, n, (blockIdx.x - NBv) * 8 + (threadIdx.x >> 6), gb * 8);
    }
}

// K5 (512thr): one block per bucket: u[d] = sum dis[s]*xw[s] (dis rides in y4.w ->
// ONE 16B gather per record, 4x unrolled for MLP), then finalize + out GEMM.
__global__ __launch_bounds__(512) void k_aggfinal(const unsigned* __restrict__ recs,
                                                  const int* __restrict__ bstart, const int* __restrict__ bcount,
                                                  const float4* __restrict__ y4, const float* __restrict__ bg,
                                                  const float* __restrict__ Wo, const float* __restrict__ bo,
                                                  float* __restrict__ outH, float* __restrict__ outZ, int n) {
    __shared__ float u[RB * 3];
    int t = threadIdx.x;
    for (int i = t; i < RB * 3; i += 512) u[i] = 0.f;
    __syncthreads();
    int b = blockIdx.x;
    int i0 = bstart[b], i1 = i0 + bcount[b];
    int i = i0 + t;
    for (; i + 1536 < i1; i += 2048) {
        unsigned r0 = recs[i], r1 = recs[i + 512], r2 = recs[i + 1024], r3 = recs[i + 1536];
        float4 v0 = y4[r0 & 0x1FFFF], v1 = y4[r1 & 0x1FFFF],
               v2 = y4[r2 & 0x1FFFF], v3 = y4[r3 & 0x1FFFF];
        atomicAdd(&u[(r0 >> 17) * 3 + 0], v0.w * v0.x);
        atomicAdd(&u[(r0 >> 17) * 3 + 1], v0.w * v0.y);
        atomicAdd(&u[(r0 >> 17) * 3 + 2], v0.w * v0.z);
        atomicAdd(&u[(r1 >> 17) * 3 + 0], v1.w * v1.x);
        atomicAdd(&u[(r1 >> 17) * 3 + 1], v1.w * v1.y);
        atomicAdd(&u[(r1 >> 17) * 3 + 2], v1.w * v1.z);
        atomicAdd(&u[(r2 >> 17) * 3 + 0], v2.w * v2.x);
        atomicAdd(&u[(r2 >> 17) * 3 + 1], v2.w * v2.y);
        atomicAdd(&u[(r2 >> 17) * 3 + 2], v2.w * v2.z);
        atomicAdd(&u[(r3 >> 17) * 3 + 0], v3.w * v3.x);
        atomicAdd(&u[(r3 >> 17) * 3 + 1], v3.w * v3.y);
        atomicAdd(&u[(r3 >> 17) * 3 + 2], v3.w * v3.z);
    }
    for (; i < i1; i += 512) {
        unsigned rec = recs[i];
        float4 v = y4[rec & 0x1FFFF];
        int r = rec >> 17;
        atomicAdd(&u[r * 3 + 0], v.w * v.x);
        atomicAdd(&u[r * 3 + 1], v.w * v.y);
        atomicAdd(&u[r * 3 + 2], v.w * v.z);
    }
    __syncthreads();
    float b0 = bg[0], b1 = bg[1], b2 = bg[2];
    int rbase = b << RBS;
    for (int r = t; r < RB; r += 512) {
        int row = rbase + r;
        if (row >= n) break;
        float4 yv = y4[row];
        float di = yv.w;
        float h0 = fmaxf(di * (u[r * 3 + 0] + di * yv.x) + b0, 0.f);
        float h1 = fmaxf(di * (u[r * 3 + 1] + di * yv.y) + b1, 0.f);
        float h2 = fmaxf(di * (u[r * 3 + 2] + di * yv.z) + b2, 0.f);
        outH[row * 3 + 0] = h0; outH[row * 3 + 1] = h1; outH[row * 3 + 2] = h2;
#pragma unroll
        for (int c = 0; c < NC; ++c)
            outZ[row * NC + c] = h0 * Wo[c] + h1 * Wo[NC + c] + h2 * Wo[2 * NC + c] + bo[c];
    }
}

// ---------- atomic fallback (round-1 structure) ----------

__global__ void k_detect_fb(const int* ei, int* flag, int E) {
    __shared__ int anynz;
    if (threadIdx.x == 0) anynz = 0;
    __syncthreads();
    int lim = E < 2048 ? E : 2048;
    int nz = 0;
    for (int i = threadIdx.x; i < lim; i += blockDim.x) nz |= ei[2 * i + 1];
    if (nz) atomicOr(&anynz, 1);
    __syncthreads();
    if (threadIdx.x == 0) *flag = anynz;
}
__global__ void k_init_fb(float* deg, int n) {
    int i = blockIdx.x * blockDim.x + threadIdx.x;
    if (i < n) deg[i] = 1.0f;
}
__global__ void k_degc_fb(const void* ei, const int* flag, float* deg, int E, int n) {
    int i = blockIdx.x * blockDim.x + threadIdx.x;
    if (i >= E) return;
    int d = load_idx(ei, (long long)E + i, *flag);
    if ((unsigned)d < (unsigned)n) atomicAdd(&deg[d], 1.0f);
}
__global__ __launch_bounds__(256) void k_gemm_fb(const float* x, const float* W, float* degdis,
                                                 float* xw, float* agg, int n) {
    __shared__ float wl[NF * NH];
    for (int j = threadIdx.x; j < NF * NH; j += 256) wl[j] = W[j];
    __syncthreads();
    int row = blockIdx.x * 4 + (threadIdx.x >> 6);
    if (row >= n) return;
    int lane = threadIdx.x & 63;
    const float4* xp = (const float4*)(x + (size_t)row * NF + lane * 8);
    float4 a = xp[0], b = xp[1];
    float xv[8] = {a.x, a.y, a.z, a.w, b.x, b.y, b.z, b.w};
    float s0 = 0.f, s1 = 0.f, s2 = 0.f;
    int f0 = lane * 8;
#pragma unroll
    for (int j = 0; j < 8; ++j) {
        float v = xv[j];
        const float* wp = &wl[(f0 + j) * NH];
        s0 += v * wp[0]; s1 += v * wp[1]; s2 += v * wp[2];
    }
#pragma unroll
    for (int off = 32; off; off >>= 1) {
        s0 += __shfl_down(s0, off); s1 += __shfl_down(s1, off); s2 += __shfl_down(s2, off);
    }
    if (lane == 0) {
        float d = degdis[row];
        float di = d > 0.f ? rsqrtf(d) : 0.f;
        degdis[row] = di;
        xw[row * 3 + 0] = s0; xw[row * 3 + 1] = s1; xw[row * 3 + 2] = s2;
        float n2 = di * di;
        agg[row * 3 + 0] = s0 * n2; agg[row * 3 + 1] = s1 * n2; agg[row * 3 + 2] = s2 * n2;
    }
}
__global__ void k_scat_fb(const void* ei, const int* flag, const float* dis, const float* xw,
                          float* agg, int E, int n) {
    int i = blockIdx.x * blockDim.x + threadIdx.x;
    if (i >= E) return;
    int is32 = *flag;
    int s = load_idx(ei, i, is32);
    int d = load_idx(ei, (long long)E + i, is32);
    if ((unsigned)s >= (unsigned)n || (unsigned)d >= (unsigned)n) return;
    float w = dis[s] * dis[d];
    atomicAdd(&agg[d * 3 + 0], xw[s * 3 + 0] * w);
    atomicAdd(&agg[d * 3 + 1], xw[s * 3 + 1] * w);
    atomicAdd(&agg[d * 3 + 2], xw[s * 3 + 2] * w);
}
__global__ void k_final_fb(const float* agg, const float* bg, const float* Wo, const float* bo,
                           float* outH, float* outZ, int n) {
    int i = blockIdx.x * blockDim.x + threadIdx.x;
    if (i >= n) return;
    float h0 = fmaxf(agg[i * 3 + 0] + bg[0], 0.f);
    float h1 = fmaxf(agg[i * 3 + 1] + bg[1], 0.f);
    float h2 = fmaxf(agg[i * 3 + 2] + bg[2], 0.f);
    outH[i * 3 + 0] = h0; outH[i * 3 + 1] = h1; outH[i * 3 + 2] = h2;
#pragma unroll
    for (int c = 0; c < NC; ++c)
        outZ[i * NC + c] = h0 * Wo[c] + h1 * Wo[NC + c] + h2 * Wo[2 * NC + c] + bo[c];
}

// ---------- launch ----------

extern "C" void kernel_launch(void* const* d_in, const int* in_sizes, int n_in,
                              void* d_out, int out_size, void* d_ws, size_t ws_size,
                              hipStream_t stream) {
    const float* x  = (const float*)d_in[0];
    const void*  ei = d_in[1];
    const float* Wg = (const float*)d_in[2];
    const float* bg = (const float*)d_in[3];
    const float* Wo = (const float*)d_in[4];
    const float* bo = (const float*)d_in[5];

    const int N = in_sizes[0] / NF;
    const int E = in_sizes[1] / 2;
    const int NBv = (N + RB - 1) >> RBS;

    float* outH = (float*)d_out;
    float* outZ = outH + (size_t)3 * N;

    int*   wsI = (int*)d_ws;
    float* wsF = (float*)d_ws;

    size_t off = 64;
    int* hist   = wsI + off; off += (size_t)NBMAX * G1;
    int* bstart = wsI + off; off += NBMAX;
    int* bcount = wsI + off; off += NBMAX;
    off = (off + 3) & ~(size_t)3;
    float* y4   = wsF + off; off += (size_t)4 * N;
    unsigned* recs = (unsigned*)(wsI + off); off += E;

    bool fast = (off * 4 <= ws_size) && (N <= 131072) && (NBv <= NBMAX);

    if (fast) {
        // gemm row fractions sized to estimated CSR phase durations
        int r1 = (int)((long long)N * 20 / 100);
        int r2 = (int)((long long)N * 28 / 100);
        int r3 = (int)((long long)N * 78 / 100);
        k_histgemm<<<G1 + 384, dim3(512), 0, stream>>>(ei, hist, E, NBv, x, Wg, y4, r1);
        k_scangemm<<<NBv + 256, dim3(256), 0, stream>>>(hist, bcount, NBv, x, Wg, y4, r1, r2);
        k_sortgemm<<<G1 + 512, dim3(512), 0, stream>>>(ei, hist, bcount, bstart, recs, E, NBv,
                                                       x, Wg, y4, r2, r3);
        k_deggemm<<<NBv + 256, dim3(512), 0, stream>>>(recs, bstart, bcount, y4, N, NBv, x, Wg, r3);
        k_aggfinal<<<NBv, dim3(512), 0, stream>>>(recs, bstart, bcount, (const float4*)y4,
                                                  bg, Wo, bo, outH, outZ, N);
    } else {
        int* flag  = wsI;
        float* deg = wsF + 64;
        float* xw  = deg + N;
        float* agg = xw + (size_t)3 * N;
        int gN = (N + 255) / 256, gE = (E + 255) / 256;
        dim3 blk(256);
        k_detect_fb<<<1, blk, 0, stream>>>((const int*)ei, flag, E);
        k_init_fb<<<gN, blk, 0, stream>>>(deg, N);
        k_degc_fb<<<gE, blk, 0, stream>>>(ei, flag, deg, E, N);
        k_gemm_fb<<<(N + 3) / 4, blk, 0, stream>>>(x, Wg, deg, xw, agg, N);
        k_scat_fb<<<gE, blk, 0, stream>>>(ei, flag, deg, xw, agg, E, N);
        k_final_fb<<<gN, blk, 0, stream>>>(agg, bg, Wo, bo, outH, outZ, N);
    }
}